// Round 1
// baseline (930.626 us; speedup 1.0000x reference)
//
#include <hip/hip_runtime.h>

// Problem constants (fixed by setup_inputs)
#define NT   32768      // B*T tokens
#define NV   32         // V
#define DI   64         // I == H
#define VI   2048       // V*I

typedef __attribute__((ext_vector_type(8)))  short short8;    // 8 bf16 (4 VGPRs)
typedef __attribute__((ext_vector_type(16))) float floatx16;  // MFMA 32x32 acc

#define MFMA32(a,b,c) __builtin_amdgcn_mfma_f32_32x32x16_bf16(a, b, c, 0, 0, 0)

// ---- workspace layout (bytes) ----
// S     : fp32 [NT][64]  (skip|elu(h1))          @ 0         (8,388,608)
// wbuf  : fp32 [NT][32]  (softmax weights)       @ 8388608   (4,194,304)
// WcombT: bf16 [64][2048] (A for weight GEMM)    @ 12582912  (262,144)
// wAv   : bf16 [32][256][88] (augmented A tiles) @ 12845056  (1,441,792)
#define WS_S      0
#define WS_WBUF   8388608
#define WS_WCOMBT 12582912
#define WS_WAV    12845056

static __device__ __forceinline__ unsigned short f2bf(float f) {
    union { float f; unsigned u; } v; v.f = f;
    unsigned r = v.u + 0x7FFFu + ((v.u >> 16) & 1u);   // RNE
    return (unsigned short)(r >> 16);
}
static __device__ __forceinline__ unsigned pk2bf(float lo, float hi) {
    return (unsigned)f2bf(lo) | ((unsigned)f2bf(hi) << 16);
}
// single-instruction packed f32->bf16 (RNE), replaces ~10 VALU ops per pair
static __device__ __forceinline__ unsigned cvtpk(float lo, float hi) {
    unsigned r;
    asm("v_cvt_pk_bf16_f32 %0, %1, %2" : "=v"(r) : "v"(lo), "v"(hi));
    return r;
}
static __device__ __forceinline__ float elu1(float v) {
    return (v > 0.f) ? v : (__expf(v) - 1.f);
}

// ============================================================================
// K0: convert + transpose + bias-augment weights to bf16 in ws.
//  WcombT[n][k] = n<32 ? Ws[k][n] : W1[k][n-32]
//  wAv[v][r][c]: r<64: W1a (A[m=h][k=i], col64=b1), r<128: W2a, r>=128: Wga.
//  cols 65..87 zero (K padded to 80 in steps of 16; cols 80..87 never read).
// ============================================================================
__global__ void k0_prep(const float* __restrict__ wg_W1, const float* __restrict__ wg_Ws,
                        const float* __restrict__ v_W1, const float* __restrict__ v_b1,
                        const float* __restrict__ v_W2, const float* __restrict__ v_b2,
                        const float* __restrict__ v_Wg, const float* __restrict__ v_bg,
                        unsigned short* __restrict__ WcombT, unsigned short* __restrict__ wAv) {
    int tid = blockIdx.x * blockDim.x + threadIdx.x;
    int stride = gridDim.x * blockDim.x;
    for (int i = tid; i < 64 * 2048; i += stride) {
        int n = i >> 11, k = i & 2047;
        float val = (n < 32) ? wg_Ws[k * 32 + n] : wg_W1[k * 32 + (n - 32)];
        WcombT[i] = f2bf(val);
    }
    for (int i = tid; i < 32 * 256 * 88; i += stride) {
        int v  = i / (256 * 88);
        int rm = i - v * (256 * 88);
        int r  = rm / 88, c = rm - r * 88;
        float val = 0.f;
        if (r < 64) {
            if (c < 64)       val = v_W1[(v * 64 + c) * 64 + r];
            else if (c == 64) val = v_b1[v * 64 + r];
        } else if (r < 128) {
            int m = r - 64;
            if (c < 64)       val = v_W2[(v * 64 + c) * 64 + m];
            else if (c == 64) val = v_b2[v * 64 + m];
        } else {
            int m = r - 128;
            if (c < 64)       val = v_Wg[(v * 64 + c) * 128 + m];
            else if (c == 64) val = v_bg[v * 128 + m];
        }
        wAv[i] = f2bf(val);
    }
}

// ============================================================================
// K1: S = [skip | elu(h1)] = flat @ [Ws|W1] + [bs|b1], M=32768 K=2048 N=64.
// Transposed: A = WcombT (M=64 outputs), B = x (N=tokens, K-contiguous/lane).
// No LDS staging: B frags straight from global (8 consecutive fp32/lane),
// A frags from L2-resident WcombT. K split 4x across waves; LDS reduce.
// ============================================================================
__launch_bounds__(256, 4)
__global__ void k1_wgemm(const float* __restrict__ x, const unsigned short* __restrict__ WcombT,
                         const float* __restrict__ wg_bs, const float* __restrict__ wg_b1,
                         float* __restrict__ S) {
    __shared__ float Cbuf[4 * 64 * 33];   // [wave][outdim 64][tok 32+pad]
    int tid  = threadIdx.x;
    int wv   = tid >> 6;
    int lane = tid & 63;
    int l31  = lane & 31, s = lane >> 5;
    int tile = blockIdx.x;                             // 1024 tiles x 32 tokens
    long tok = (long)tile * 32 + l31;

    const float*          xrow = x + tok * VI + wv * 512 + s * 8;
    const unsigned short* a0p  = WcombT + (l31)      * 2048 + wv * 512 + s * 8;
    const unsigned short* a1p  = WcombT + (l31 + 32) * 2048 + wv * 512 + s * 8;

    floatx16 acc0 = {}; floatx16 acc1 = {};
    #pragma unroll 4
    for (int ks = 0; ks < 32; ++ks) {
        int ko = ks * 16;
        short8 af0 = *(const short8*)(a0p + ko);
        short8 af1 = *(const short8*)(a1p + ko);
        float4 xa = *(const float4*)(xrow + ko);
        float4 xb = *(const float4*)(xrow + ko + 4);
        union { unsigned u[4]; short8 s8; } bp;
        bp.u[0] = pk2bf(xa.x, xa.y);
        bp.u[1] = pk2bf(xa.z, xa.w);
        bp.u[2] = pk2bf(xb.x, xb.y);
        bp.u[3] = pk2bf(xb.z, xb.w);
        acc0 = MFMA32(af0, bp.s8, acc0);
        acc1 = MFMA32(af1, bp.s8, acc1);
    }
    // partial C -> LDS.  C layout: col=lane&31(tok), row=(reg&3)+8*(reg>>2)+4*s
    float* cb = Cbuf + wv * (64 * 33);
    #pragma unroll
    for (int reg = 0; reg < 16; ++reg) {
        int r0 = (reg & 3) + 8 * (reg >> 2) + 4 * s;
        cb[(r0)*33 + l31]      = acc0[reg];
        cb[(r0 + 32)*33 + l31] = acc1[reg];
    }
    __syncthreads();
    // reduce 4 K-partials + bias/elu epilogue; coalesced stores
    int n  = tid & 63;
    int tb = (tid >> 6) * 8;
    #pragma unroll
    for (int g = 0; g < 8; ++g) {
        int t = tb + g;
        float v = Cbuf[0*2112 + n*33 + t] + Cbuf[1*2112 + n*33 + t]
                + Cbuf[2*2112 + n*33 + t] + Cbuf[3*2112 + n*33 + t];
        if (n < 32) v += wg_bs[n];
        else        v = elu1(v + wg_b1[n - 32]);
        S[((long)tile * 32 + t) * 64 + n] = v;
    }
}

// ============================================================================
// K2: per-token h2 = h1e@W2+b2 ; z = h2@Wg+bg ; w = softmax(LN(skip+glu(z)))
// One wave per token; lanes 0..63 hold S row; shuffles for the tiny matmuls.
// ============================================================================
__launch_bounds__(256, 4)
__global__ void k2_token(const float* __restrict__ S,
                         const float* __restrict__ wg_W2, const float* __restrict__ wg_b2,
                         const float* __restrict__ wg_Wg, const float* __restrict__ wg_bg,
                         const float* __restrict__ wg_gamma, const float* __restrict__ wg_beta,
                         float* __restrict__ wout) {
    int tid = threadIdx.x;
    int wv = tid >> 6, lane = tid & 63;
    int l31 = lane & 31;
    long t = (long)blockIdx.x * 4 + wv;
    float sv = S[t * 64 + lane];
    // h2[j], duplicated on both halves (j = l31)
    float h2 = wg_b2[l31];
    #pragma unroll
    for (int k = 0; k < 32; ++k) {
        float h1e = __shfl(sv, 32 + k);
        h2 += h1e * wg_W2[k * 32 + l31];
    }
    // z[lane] over 64 outputs
    float z = wg_bg[lane];
    #pragma unroll
    for (int k = 0; k < 32; ++k) {
        float hk = __shfl(h2, k);
        z += hk * wg_Wg[k * 64 + lane];
    }
    float za   = __shfl(z, l31);
    float zg   = __shfl(z, l31 + 32);
    float skip = __shfl(sv, l31);
    float y = skip + za / (1.f + __expf(-zg));      // skip + glu(z)
    // LN over 32 (data duplicated with period 32 -> xor masks <=16 are safe)
    float s1 = y;
    #pragma unroll
    for (int m = 1; m <= 16; m <<= 1) s1 += __shfl_xor(s1, m);
    float mean = s1 * (1.f / 32.f);
    float d = y - mean;
    float s2 = d * d;
    #pragma unroll
    for (int m = 1; m <= 16; m <<= 1) s2 += __shfl_xor(s2, m);
    float rinv  = rsqrtf(s2 * (1.f / 32.f) + 1e-5f);
    float logit = d * rinv * wg_gamma[l31] + wg_beta[l31];
    // softmax over 32
    float mx = logit;
    #pragma unroll
    for (int m = 1; m <= 16; m <<= 1) mx = fmaxf(mx, __shfl_xor(mx, m));
    float e = __expf(logit - mx);
    float se = e;
    #pragma unroll
    for (int m = 1; m <= 16; m <<= 1) se += __shfl_xor(se, m);
    if (lane < 32) wout[t * 32 + lane] = e / se;
}

// ============================================================================
// K3: per-variable GRNs + weighted combine (transposed MFMA chain).
// v2: latency-focused rework.
//  - A-frags read DIRECTLY from global (wAv is L2/L3-resident, 1.4 MB) ->
//    no weight LDS staging, no 4-way-conflicted wA reads, LDS 77->37 KB.
//  - Grid 1024 = 256 token-tiles x 4 var-quarters (8 vars each) so ~3
//    blocks/CU can be resident (launch_bounds(256,3)); 4-way out atomics.
//  - T14 async-STAGE: next var's x-tile loaded to registers after the g
//    MFMAs (past peak VGPR pressure), LDS-written after next top barrier.
//  - VALU diet: v_cvt_pk_bf16_f32 packing, v_rcp for sigmoid, v_rsq for LN,
//    skip connection read as 8x ds_read_b128 instead of 32 scalar reads.
// ============================================================================
static __device__ __forceinline__ void tile_to_bfrags(const float* t16, int sh,
                                                      short8* f0, short8* f1) {
    unsigned P[8];
    #pragma unroll
    for (int i = 0; i < 8; ++i) P[i] = cvtpk(t16[2 * i], t16[2 * i + 1]);
    unsigned X[8];
    #pragma unroll
    for (int i = 0; i < 8; ++i) X[i] = (unsigned)__shfl_xor((int)P[i], 32);
    union { unsigned u[4]; short8 s8; } a, b;
    a.u[0] = sh ? X[2] : P[0];  a.u[1] = sh ? X[3] : P[1];
    a.u[2] = sh ? P[2] : X[0];  a.u[3] = sh ? P[3] : X[1];
    b.u[0] = sh ? X[6] : P[4];  b.u[1] = sh ? X[7] : P[5];
    b.u[2] = sh ? P[6] : X[4];  b.u[3] = sh ? P[7] : X[5];
    *f0 = a.s8; *f1 = b.s8;
}

__launch_bounds__(256, 3)
__global__ void k3_vgrn(const float* __restrict__ x, const unsigned short* __restrict__ wAv,
                        const float* __restrict__ v_gamma, const float* __restrict__ v_beta,
                        const float* __restrict__ wbuf, float* __restrict__ out) {
    __shared__ float xt[128 * 65];     // fp32 x tile, pad 65 (odd -> conflict-free)
    __shared__ float gbAll[8 * 128];   // gamma/beta interleaved, all 8 vars of quarter
    int tid  = threadIdx.x;
    int wv   = tid >> 6, lane = tid & 63;
    int l31  = lane & 31, s = lane >> 5;
    int tile = blockIdx.x >> 2;                          // 256 token tiles
    int vq   = blockIdx.x & 3;                           // variable quarter (8 vars)
    int tl   = wv * 32 + l31;                            // token within tile
    long tokg = (long)tile * 128 + tl;

    float outacc[32];
    #pragma unroll
    for (int i = 0; i < 32; ++i) outacc[i] = 0.f;

    // ones B-frag: k=64 (bias col) -> s=0,j=0 only
    union { unsigned u[4]; short8 s8; } onef;
    onef.u[0] = (s == 0) ? 0x00003F80u : 0u;
    onef.u[1] = 0; onef.u[2] = 0; onef.u[3] = 0;

    // ---- preload gamma/beta for all 8 vars of this quarter (once) ----
    for (int i = tid; i < 8 * 128; i += 256) {
        int j = i >> 7, t2 = i & 127, h = t2 >> 1;
        gbAll[i] = (t2 & 1) ? v_beta[(vq * 8 + j) * 64 + h]
                            : v_gamma[(vq * 8 + j) * 64 + h];
    }

    // ---- prefetch x-tile for it=0 into registers ----
    float4 rx[8];
    {
        const float* xs = x + ((long)tile * 128 * NV + vq * 8) * DI;
        #pragma unroll
        for (int i2 = 0; i2 < 8; ++i2) {
            int idx = i2 * 256 + tid, row = idx >> 4, c4 = (idx & 15) * 4;
            rx[i2] = *(const float4*)(xs + (long)row * VI + c4);
        }
    }

    for (int it = 0; it < 8; ++it) {
        int vg = vq * 8 + it;
        __syncthreads();    // previous iteration's xt readers done
        // ---- write prefetched x tile to LDS ----
        #pragma unroll
        for (int i2 = 0; i2 < 8; ++i2) {
            int idx = i2 * 256 + tid, row = idx >> 4, c4 = (idx & 15) * 4;
            *(float4*)(xt + row * 65 + c4) = rx[i2];
        }
        __syncthreads();

        // ---- x B-frags (4 ksteps of 16) ----
        short8 xb[4];
        const float* xr = xt + tl * 65 + s * 8;
        #pragma unroll
        for (int ks = 0; ks < 4; ++ks) {
            const float* p = xr + ks * 16;
            union { unsigned u[4]; short8 s8; } bp;
            bp.u[0] = cvtpk(p[0], p[1]);
            bp.u[1] = cvtpk(p[2], p[3]);
            bp.u[2] = cvtpk(p[4], p[5]);
            bp.u[3] = cvtpk(p[6], p[7]);
            xb[ks] = bp.s8;
        }

        // A-frags straight from global (L2-resident)
        const unsigned short* Ab = wAv + (size_t)vg * (256 * 88) + l31 * 88 + s * 8;

        // ---- H1T = W1a @ [XT;1] ----
        floatx16 h1a0 = {}, h1a1 = {};
        #pragma unroll
        for (int ks = 0; ks < 5; ++ks) {
            short8 b = (ks < 4) ? xb[ks] : onef.s8;
            h1a0 = MFMA32(*(const short8*)(Ab + (0)  * 88 + ks * 16), b, h1a0);
            h1a1 = MFMA32(*(const short8*)(Ab + (32) * 88 + ks * 16), b, h1a1);
        }
        short8 h1b[4];
        {
            float t16[16];
            #pragma unroll
            for (int r = 0; r < 16; ++r) t16[r] = elu1(h1a0[r]);
            tile_to_bfrags(t16, s, &h1b[0], &h1b[1]);
            #pragma unroll
            for (int r = 0; r < 16; ++r) t16[r] = elu1(h1a1[r]);
            tile_to_bfrags(t16, s, &h1b[2], &h1b[3]);
        }
        // ---- H2T = W2a @ [H1T;1]  (linear, no activation) ----
        floatx16 h2a0 = {}, h2a1 = {};
        #pragma unroll
        for (int ks = 0; ks < 5; ++ks) {
            short8 b = (ks < 4) ? h1b[ks] : onef.s8;
            h2a0 = MFMA32(*(const short8*)(Ab + (64) * 88 + ks * 16), b, h2a0);
            h2a1 = MFMA32(*(const short8*)(Ab + (96) * 88 + ks * 16), b, h2a1);
        }
        short8 h2b[4];
        {
            float t16[16];
            #pragma unroll
            for (int r = 0; r < 16; ++r) t16[r] = h2a0[r];
            tile_to_bfrags(t16, s, &h2b[0], &h2b[1]);
            #pragma unroll
            for (int r = 0; r < 16; ++r) t16[r] = h2a1[r];
            tile_to_bfrags(t16, s, &h2b[2], &h2b[3]);
        }
        // ---- GT = Wga @ [H2T;1] : rows 0..63 = a, 64..127 = gate ----
        floatx16 g0 = {}, g1 = {}, g2 = {}, g3 = {};
        #pragma unroll
        for (int ks = 0; ks < 5; ++ks) {
            short8 b = (ks < 4) ? h2b[ks] : onef.s8;
            g0 = MFMA32(*(const short8*)(Ab + (128) * 88 + ks * 16), b, g0);
            g1 = MFMA32(*(const short8*)(Ab + (160) * 88 + ks * 16), b, g1);
            g2 = MFMA32(*(const short8*)(Ab + (192) * 88 + ks * 16), b, g2);
            g3 = MFMA32(*(const short8*)(Ab + (224) * 88 + ks * 16), b, g3);
        }

        // ---- prefetch next var's x tile (hidden under glu/LN/accumulate;
        //      drained by the vmcnt(0) at next iteration's top barrier) ----
        if (it < 7) {
            const float* xs = x + ((long)tile * 128 * NV + vg + 1) * DI;
            #pragma unroll
            for (int i2 = 0; i2 < 8; ++i2) {
                int idx = i2 * 256 + tid, row = idx >> 4, c4 = (idx & 15) * 4;
                rx[i2] = *(const float4*)(xs + (long)row * VI + c4);
            }
        }

        // ---- skip (vector ds_reads) + glu + LN + weighted combine ----
        float y[32];
        const float* skp = xt + tl * 65 + 4 * s;
        #pragma unroll
        for (int q = 0; q < 4; ++q) {
            float4 a4 = *(const float4*)(skp + q * 8);
            float4 b4 = *(const float4*)(skp + q * 8 + 32);
            y[q * 4 + 0] = a4.x; y[q * 4 + 1] = a4.y;
            y[q * 4 + 2] = a4.z; y[q * 4 + 3] = a4.w;
            y[16 + q * 4 + 0] = b4.x; y[16 + q * 4 + 1] = b4.y;
            y[16 + q * 4 + 2] = b4.z; y[16 + q * 4 + 3] = b4.w;
        }
        #pragma unroll
        for (int r = 0; r < 16; ++r) {
            y[r]      += g0[r] * __builtin_amdgcn_rcpf(1.f + __expf(-g2[r]));
            y[16 + r] += g1[r] * __builtin_amdgcn_rcpf(1.f + __expf(-g3[r]));
        }
        float s1 = 0.f;
        #pragma unroll
        for (int i = 0; i < 32; ++i) s1 += y[i];
        s1 += __shfl_xor(s1, 32);
        float mean = s1 * (1.f / 64.f);
        float s2 = 0.f;
        #pragma unroll
        for (int i = 0; i < 32; ++i) { float d = y[i] - mean; s2 += d * d; }
        s2 += __shfl_xor(s2, 32);
        float rinv = __builtin_amdgcn_rsqf(s2 * (1.f / 64.f) + 1e-5f);
        float wvv = wbuf[tokg * 32 + vg];
        const float* gbp = gbAll + it * 128;
        #pragma unroll
        for (int r = 0; r < 16; ++r) {
            int hr = (r & 3) + 8 * (r >> 2) + 4 * s;
            float pv0 = (y[r]      - mean) * rinv * gbp[2 * hr]          + gbp[2 * hr + 1];
            float pv1 = (y[16 + r] - mean) * rinv * gbp[2 * (hr + 32)]   + gbp[2 * (hr + 32) + 1];
            outacc[r]      += wvv * pv0;
            outacc[16 + r] += wvv * pv1;
        }
    }
    // ---- combine the four v-quarter blocks via atomics ----
    #pragma unroll
    for (int r = 0; r < 16; ++r) {
        int hr = (r & 3) + 8 * (r >> 2) + 4 * s;
        atomicAdd(out + tokg * 64 + hr,      outacc[r]);
        atomicAdd(out + tokg * 64 + 32 + hr, outacc[16 + r]);
    }
}

// ============================================================================
extern "C" void kernel_launch(void* const* d_in, const int* in_sizes, int n_in,
                              void* d_out, int out_size, void* d_ws, size_t ws_size,
                              hipStream_t stream) {
    const float* x        = (const float*)d_in[0];
    const float* wg_W1    = (const float*)d_in[1];
    const float* wg_b1    = (const float*)d_in[2];
    const float* wg_W2    = (const float*)d_in[3];
    const float* wg_b2    = (const float*)d_in[4];
    const float* wg_Wg    = (const float*)d_in[5];
    const float* wg_bg    = (const float*)d_in[6];
    const float* wg_Ws    = (const float*)d_in[7];
    const float* wg_bs    = (const float*)d_in[8];
    const float* wg_gamma = (const float*)d_in[9];
    const float* wg_beta  = (const float*)d_in[10];
    const float* v_W1     = (const float*)d_in[11];
    const float* v_b1     = (const float*)d_in[12];
    const float* v_W2     = (const float*)d_in[13];
    const float* v_b2     = (const float*)d_in[14];
    const float* v_Wg     = (const float*)d_in[15];
    const float* v_bg     = (const float*)d_in[16];
    const float* v_gamma  = (const float*)d_in[17];
    const float* v_beta   = (const float*)d_in[18];
    (void)in_sizes; (void)n_in; (void)ws_size;

    char* ws = (char*)d_ws;
    float* S               = (float*)(ws + WS_S);
    float* wbuf            = (float*)(ws + WS_WBUF);
    unsigned short* WcombT = (unsigned short*)(ws + WS_WCOMBT);
    unsigned short* wAv    = (unsigned short*)(ws + WS_WAV);
    float* out             = (float*)d_out;

    hipMemsetAsync(d_out, 0, (size_t)out_size * sizeof(float), stream);
    k0_prep<<<512, 256, 0, stream>>>(wg_W1, wg_Ws, v_W1, v_b1, v_W2, v_b2, v_Wg, v_bg,
                                     WcombT, wAv);
    k1_wgemm<<<1024, 256, 0, stream>>>(x, WcombT, wg_bs, wg_b1, S);
    k2_token<<<8192, 256, 0, stream>>>(S, wg_W2, wg_b2, wg_Wg, wg_bg, wg_gamma, wg_beta, wbuf);
    k3_vgrn<<<1024, 256, 0, stream>>>(x, wAv, v_gamma, v_beta, wbuf, out);
}

// Round 2
// 648.093 us; speedup vs baseline: 1.4359x; 1.4359x over previous
//
#include <hip/hip_runtime.h>

// Problem constants (fixed by setup_inputs)
#define NT   32768      // B*T tokens
#define NV   32         // V
#define DI   64         // I == H
#define VI   2048       // V*I

typedef __attribute__((ext_vector_type(8)))  short short8;    // 8 bf16 (4 VGPRs)
typedef __attribute__((ext_vector_type(16))) float floatx16;  // MFMA 32x32 acc

#define MFMA32(a,b,c) __builtin_amdgcn_mfma_f32_32x32x16_bf16(a, b, c, 0, 0, 0)

// ---- workspace layout (bytes) ----
// S     : fp32 [NT][64]  (skip|elu(h1))          @ 0         (8,388,608)
// wbuf  : fp32 [NT][32]  (softmax weights)       @ 8388608   (4,194,304)
// WcombT: bf16 [64][2048] (A for weight GEMM)    @ 12582912  (262,144)
// wAv   : bf16 [32][256][88] (augmented A tiles) @ 12845056  (1,441,792)
#define WS_S      0
#define WS_WBUF   8388608
#define WS_WCOMBT 12582912
#define WS_WAV    12845056

// async global->LDS, 16B/lane; LDS dest = wave-uniform base + lane*16 (m104/m108)
#define GLDS(g, l) __builtin_amdgcn_global_load_lds( \
    (const __attribute__((address_space(1))) unsigned int*)(g), \
    (__attribute__((address_space(3))) unsigned int*)(l), 16, 0, 0)

static __device__ __forceinline__ unsigned short f2bf(float f) {
    union { float f; unsigned u; } v; v.f = f;
    unsigned r = v.u + 0x7FFFu + ((v.u >> 16) & 1u);   // RNE
    return (unsigned short)(r >> 16);
}
static __device__ __forceinline__ unsigned pk2bf(float lo, float hi) {
    return (unsigned)f2bf(lo) | ((unsigned)f2bf(hi) << 16);
}
// single-instruction packed f32->bf16 (RNE)
static __device__ __forceinline__ unsigned cvtpk(float lo, float hi) {
    unsigned r;
    asm("v_cvt_pk_bf16_f32 %0, %1, %2" : "=v"(r) : "v"(lo), "v"(hi));
    return r;
}
static __device__ __forceinline__ float elu1(float v) {
    return (v > 0.f) ? v : (__expf(v) - 1.f);
}

// ============================================================================
// K0: convert + transpose + bias-augment weights to bf16 in ws.
//  WcombT[n][k] = n<32 ? Ws[k][n] : W1[k][n-32]
//  wAv[v][r][c]: r<64: W1a (A[m=h][k=i], col64=b1), r<128: W2a, r>=128: Wga.
//  cols 65..87 zero (K padded to 80 in steps of 16; cols 80..87 never read).
// ============================================================================
__global__ void k0_prep(const float* __restrict__ wg_W1, const float* __restrict__ wg_Ws,
                        const float* __restrict__ v_W1, const float* __restrict__ v_b1,
                        const float* __restrict__ v_W2, const float* __restrict__ v_b2,
                        const float* __restrict__ v_Wg, const float* __restrict__ v_bg,
                        unsigned short* __restrict__ WcombT, unsigned short* __restrict__ wAv) {
    int tid = blockIdx.x * blockDim.x + threadIdx.x;
    int stride = gridDim.x * blockDim.x;
    for (int i = tid; i < 64 * 2048; i += stride) {
        int n = i >> 11, k = i & 2047;
        float val = (n < 32) ? wg_Ws[k * 32 + n] : wg_W1[k * 32 + (n - 32)];
        WcombT[i] = f2bf(val);
    }
    for (int i = tid; i < 32 * 256 * 88; i += stride) {
        int v  = i / (256 * 88);
        int rm = i - v * (256 * 88);
        int r  = rm / 88, c = rm - r * 88;
        float val = 0.f;
        if (r < 64) {
            if (c < 64)       val = v_W1[(v * 64 + c) * 64 + r];
            else if (c == 64) val = v_b1[v * 64 + r];
        } else if (r < 128) {
            int m = r - 64;
            if (c < 64)       val = v_W2[(v * 64 + c) * 64 + m];
            else if (c == 64) val = v_b2[v * 64 + m];
        } else {
            int m = r - 128;
            if (c < 64)       val = v_Wg[(v * 64 + c) * 128 + m];
            else if (c == 64) val = v_bg[v * 128 + m];
        }
        wAv[i] = f2bf(val);
    }
}

// ============================================================================
// K1: S = [skip | elu(h1)] = flat @ [Ws|W1] + [bs|b1], M=32768 K=2048 N=64.
// ============================================================================
__launch_bounds__(256, 4)
__global__ void k1_wgemm(const float* __restrict__ x, const unsigned short* __restrict__ WcombT,
                         const float* __restrict__ wg_bs, const float* __restrict__ wg_b1,
                         float* __restrict__ S) {
    __shared__ float Cbuf[4 * 64 * 33];   // [wave][outdim 64][tok 32+pad]
    int tid  = threadIdx.x;
    int wv   = tid >> 6;
    int lane = tid & 63;
    int l31  = lane & 31, s = lane >> 5;
    int tile = blockIdx.x;                             // 1024 tiles x 32 tokens
    long tok = (long)tile * 32 + l31;

    const float*          xrow = x + tok * VI + wv * 512 + s * 8;
    const unsigned short* a0p  = WcombT + (l31)      * 2048 + wv * 512 + s * 8;
    const unsigned short* a1p  = WcombT + (l31 + 32) * 2048 + wv * 512 + s * 8;

    floatx16 acc0 = {}; floatx16 acc1 = {};
    #pragma unroll 4
    for (int ks = 0; ks < 32; ++ks) {
        int ko = ks * 16;
        short8 af0 = *(const short8*)(a0p + ko);
        short8 af1 = *(const short8*)(a1p + ko);
        float4 xa = *(const float4*)(xrow + ko);
        float4 xb = *(const float4*)(xrow + ko + 4);
        union { unsigned u[4]; short8 s8; } bp;
        bp.u[0] = pk2bf(xa.x, xa.y);
        bp.u[1] = pk2bf(xa.z, xa.w);
        bp.u[2] = pk2bf(xb.x, xb.y);
        bp.u[3] = pk2bf(xb.z, xb.w);
        acc0 = MFMA32(af0, bp.s8, acc0);
        acc1 = MFMA32(af1, bp.s8, acc1);
    }
    // partial C -> LDS.  C layout: col=lane&31(tok), row=(reg&3)+8*(reg>>2)+4*s
    float* cb = Cbuf + wv * (64 * 33);
    #pragma unroll
    for (int reg = 0; reg < 16; ++reg) {
        int r0 = (reg & 3) + 8 * (reg >> 2) + 4 * s;
        cb[(r0)*33 + l31]      = acc0[reg];
        cb[(r0 + 32)*33 + l31] = acc1[reg];
    }
    __syncthreads();
    // reduce 4 K-partials + bias/elu epilogue; coalesced stores
    int n  = tid & 63;
    int tb = (tid >> 6) * 8;
    #pragma unroll
    for (int g = 0; g < 8; ++g) {
        int t = tb + g;
        float v = Cbuf[0*2112 + n*33 + t] + Cbuf[1*2112 + n*33 + t]
                + Cbuf[2*2112 + n*33 + t] + Cbuf[3*2112 + n*33 + t];
        if (n < 32) v += wg_bs[n];
        else        v = elu1(v + wg_b1[n - 32]);
        S[((long)tile * 32 + t) * 64 + n] = v;
    }
}

// ============================================================================
// K2: per-token h2 = h1e@W2+b2 ; z = h2@Wg+bg ; w = softmax(LN(skip+glu(z)))
// ============================================================================
__launch_bounds__(256, 4)
__global__ void k2_token(const float* __restrict__ S,
                         const float* __restrict__ wg_W2, const float* __restrict__ wg_b2,
                         const float* __restrict__ wg_Wg, const float* __restrict__ wg_bg,
                         const float* __restrict__ wg_gamma, const float* __restrict__ wg_beta,
                         float* __restrict__ wout) {
    int tid = threadIdx.x;
    int wv = tid >> 6, lane = tid & 63;
    int l31 = lane & 31;
    long t = (long)blockIdx.x * 4 + wv;
    float sv = S[t * 64 + lane];
    float h2 = wg_b2[l31];
    #pragma unroll
    for (int k = 0; k < 32; ++k) {
        float h1e = __shfl(sv, 32 + k);
        h2 += h1e * wg_W2[k * 32 + l31];
    }
    float z = wg_bg[lane];
    #pragma unroll
    for (int k = 0; k < 32; ++k) {
        float hk = __shfl(h2, k);
        z += hk * wg_Wg[k * 64 + lane];
    }
    float za   = __shfl(z, l31);
    float zg   = __shfl(z, l31 + 32);
    float skip = __shfl(sv, l31);
    float y = skip + za / (1.f + __expf(-zg));      // skip + glu(z)
    float s1 = y;
    #pragma unroll
    for (int m = 1; m <= 16; m <<= 1) s1 += __shfl_xor(s1, m);
    float mean = s1 * (1.f / 32.f);
    float d = y - mean;
    float s2 = d * d;
    #pragma unroll
    for (int m = 1; m <= 16; m <<= 1) s2 += __shfl_xor(s2, m);
    float rinv  = rsqrtf(s2 * (1.f / 32.f) + 1e-5f);
    float logit = d * rinv * wg_gamma[l31] + wg_beta[l31];
    float mx = logit;
    #pragma unroll
    for (int m = 1; m <= 16; m <<= 1) mx = fmaxf(mx, __shfl_xor(mx, m));
    float e = __expf(logit - mx);
    float se = e;
    #pragma unroll
    for (int m = 1; m <= 16; m <<= 1) se += __shfl_xor(se, m);
    if (lane < 32) wout[t * 32 + lane] = e / se;
}

// ============================================================================
// K3: per-variable GRNs + weighted combine (transposed MFMA chain).
// v3: async single-buffer pipeline via global_load_lds (zero-VGPR staging).
//  - round-0 structure restored: 512 blocks = 256 tiles x 2 v-halves,
//    weights in LDS, 2-way atomics (round-1's global A-frags = 64-line
//    scatter per instr saturated the TA pipe; 4-way atomics doubled HBM
//    RMW writes -> both reverted).
//  - staging: next var's x (8 GLDS/wave) + weights (11 GLDS/wave) issued
//    right after the readers-done barrier; in flight across the epilogue;
//    drained by the compiler's vmcnt(0) at the next top barrier.
//  - xt is LINEAR [128][64] (GLDS requires contiguous dest); bank conflicts
//    fixed by a 16B-granule XOR swizzle: phys_unit = logical_unit ^ (row&7),
//    applied on the GLOBAL source addr at stage time and on every LDS read
//    (both-sides involution, rule #21).
//  - skip values preloaded to regs (sk[8]) BEFORE the readers-done barrier
//    so staging may overwrite xt during the epilogue.
//  - gamma/beta double-buffered (2x512B).
// ============================================================================
static __device__ __forceinline__ void tile_to_bfrags(const float* t16, int sh,
                                                      short8* f0, short8* f1) {
    unsigned P[8];
    #pragma unroll
    for (int i = 0; i < 8; ++i) P[i] = cvtpk(t16[2 * i], t16[2 * i + 1]);
    unsigned X[8];
    #pragma unroll
    for (int i = 0; i < 8; ++i) X[i] = (unsigned)__shfl_xor((int)P[i], 32);
    union { unsigned u[4]; short8 s8; } a, b;
    a.u[0] = sh ? X[2] : P[0];  a.u[1] = sh ? X[3] : P[1];
    a.u[2] = sh ? P[2] : X[0];  a.u[3] = sh ? P[3] : X[1];
    b.u[0] = sh ? X[6] : P[4];  b.u[1] = sh ? X[7] : P[5];
    b.u[2] = sh ? P[6] : X[4];  b.u[3] = sh ? P[7] : X[5];
    *f0 = a.s8; *f1 = b.s8;
}

__launch_bounds__(256, 2)
__global__ void k3_vgrn(const float* __restrict__ x, const unsigned short* __restrict__ wAv,
                        const float* __restrict__ v_gamma, const float* __restrict__ v_beta,
                        const float* __restrict__ wbuf, float* __restrict__ out) {
    __shared__ __align__(16) float xt[128 * 64];            // 32 KB, swizzled granules
    __shared__ __align__(16) unsigned short wA[256 * 88];   // 44 KB
    __shared__ float gb2[2][128];                           // 1 KB dbuf gamma/beta
    int tid  = threadIdx.x;
    int wv   = tid >> 6, lane = tid & 63;
    int l31  = lane & 31, s = lane >> 5;
    int tile = blockIdx.x >> 1;                          // 256 token tiles
    int vh   = blockIdx.x & 1;                           // variable half (16 vars)
    int tl   = wv * 32 + l31;                            // token within tile
    int tl7  = tl & 7;
    long tokg = (long)tile * 128 + tl;

    float outacc[32];
    #pragma unroll
    for (int i = 0; i < 32; ++i) outacc[i] = 0.f;

    // ones B-frag: k=64 (bias col) -> s=0,j=0 only
    union { unsigned u[4]; short8 s8; } onef;
    onef.u[0] = (s == 0) ? 0x00003F80u : 0u;
    onef.u[1] = 0; onef.u[2] = 0; onef.u[3] = 0;

    const unsigned short* wArow = wA + l31 * 88 + s * 8;
    const float* xbase = x + (long)tile * 128 * VI;

    // ---- prologue: stage var vh*16 ----
    {
        int nvg = vh * 16;
        const float* xv = xbase + (long)nvg * DI;
        #pragma unroll
        for (int i = 0; i < 8; ++i) {
            int g = i * 64 + lane;
            int row = wv * 32 + (g >> 4);
            int unit = g & 15;
            GLDS(xv + (long)row * VI + ((unit ^ (row & 7)) << 2),
                 (char*)xt + wv * 8192 + i * 1024);
        }
        const char* wsv = (const char*)wAv + (size_t)nvg * 45056 + wv * 11264 + lane * 16;
        char* wdl = (char*)wA + wv * 11264;
        #pragma unroll
        for (int i = 0; i < 11; ++i) GLDS(wsv + i * 1024, wdl + i * 1024);
        if (tid < 128) {
            int h = tid >> 1;
            gb2[0][tid] = (tid & 1) ? v_beta[nvg * 64 + h] : v_gamma[nvg * 64 + h];
        }
    }

    for (int it = 0; it < 16; ++it) {
        int vg = vh * 16 + it;
        __syncthreads();    // drains vmcnt -> staged xt/wA/gb2 ready for all waves

        // ---- x B-frags (4 ksteps of 16), swizzled reads ----
        const float* xrl = xt + tl * 64;
        short8 xb4[4];
        #pragma unroll
        for (int ks = 0; ks < 4; ++ks) {
            int u0 = 2 * s + 4 * ks;
            float4 xa = *(const float4*)(xrl + ((u0 ^ tl7) << 2));
            float4 xc = *(const float4*)(xrl + (((u0 + 1) ^ tl7) << 2));
            union { unsigned u[4]; short8 s8; } bp;
            bp.u[0] = cvtpk(xa.x, xa.y);
            bp.u[1] = cvtpk(xa.z, xa.w);
            bp.u[2] = cvtpk(xc.x, xc.y);
            bp.u[3] = cvtpk(xc.z, xc.w);
            xb4[ks] = bp.s8;
        }
        // ---- skip values fp32 -> regs (xt may be overwritten after barrier2) ----
        float4 sk[8];
        #pragma unroll
        for (int q = 0; q < 8; ++q) {
            int u = (s + 2 * q) ^ tl7;
            sk[q] = *(const float4*)(xrl + (u << 2));
        }
        float wvv = wbuf[tokg * 32 + vg];

        // ---- H1T = W1a @ [XT;1] ----
        floatx16 h1a0 = {}, h1a1 = {};
        #pragma unroll
        for (int ks = 0; ks < 5; ++ks) {
            short8 b = (ks < 4) ? xb4[ks] : onef.s8;
            h1a0 = MFMA32(*(const short8*)(wArow + (0)  * 88 + ks * 16), b, h1a0);
            h1a1 = MFMA32(*(const short8*)(wArow + (32) * 88 + ks * 16), b, h1a1);
        }
        short8 h1b[4];
        {
            float t16[16];
            #pragma unroll
            for (int r = 0; r < 16; ++r) t16[r] = elu1(h1a0[r]);
            tile_to_bfrags(t16, s, &h1b[0], &h1b[1]);
            #pragma unroll
            for (int r = 0; r < 16; ++r) t16[r] = elu1(h1a1[r]);
            tile_to_bfrags(t16, s, &h1b[2], &h1b[3]);
        }
        // ---- H2T = W2a @ [H1T;1] ----
        floatx16 h2a0 = {}, h2a1 = {};
        #pragma unroll
        for (int ks = 0; ks < 5; ++ks) {
            short8 b = (ks < 4) ? h1b[ks] : onef.s8;
            h2a0 = MFMA32(*(const short8*)(wArow + (64) * 88 + ks * 16), b, h2a0);
            h2a1 = MFMA32(*(const short8*)(wArow + (96) * 88 + ks * 16), b, h2a1);
        }
        short8 h2b[4];
        {
            float t16[16];
            #pragma unroll
            for (int r = 0; r < 16; ++r) t16[r] = h2a0[r];
            tile_to_bfrags(t16, s, &h2b[0], &h2b[1]);
            #pragma unroll
            for (int r = 0; r < 16; ++r) t16[r] = h2a1[r];
            tile_to_bfrags(t16, s, &h2b[2], &h2b[3]);
        }
        // ---- GT = Wga @ [H2T;1] : rows 0..63 = a, 64..127 = gate ----
        floatx16 g0 = {}, g1 = {}, g2 = {}, g3 = {};
        #pragma unroll
        for (int ks = 0; ks < 5; ++ks) {
            short8 b = (ks < 4) ? h2b[ks] : onef.s8;
            g0 = MFMA32(*(const short8*)(wArow + (128) * 88 + ks * 16), b, g0);
            g1 = MFMA32(*(const short8*)(wArow + (160) * 88 + ks * 16), b, g1);
            g2 = MFMA32(*(const short8*)(wArow + (192) * 88 + ks * 16), b, g2);
            g3 = MFMA32(*(const short8*)(wArow + (224) * 88 + ks * 16), b, g3);
        }

        __syncthreads();    // all xt/wA readers done -> safe to restage
        // ---- issue next var's staging (flies across the epilogue) ----
        if (it < 15) {
            int nvg = vg + 1;
            const float* xv = xbase + (long)nvg * DI;
            #pragma unroll
            for (int i = 0; i < 8; ++i) {
                int g = i * 64 + lane;
                int row = wv * 32 + (g >> 4);
                int unit = g & 15;
                GLDS(xv + (long)row * VI + ((unit ^ (row & 7)) << 2),
                     (char*)xt + wv * 8192 + i * 1024);
            }
            const char* wsv = (const char*)wAv + (size_t)nvg * 45056 + wv * 11264 + lane * 16;
            char* wdl = (char*)wA + wv * 11264;
            #pragma unroll
            for (int i = 0; i < 11; ++i) GLDS(wsv + i * 1024, wdl + i * 1024);
            if (tid < 128) {
                int h = tid >> 1;
                gb2[(it + 1) & 1][tid] = (tid & 1) ? v_beta[nvg * 64 + h]
                                                   : v_gamma[nvg * 64 + h];
            }
        }

        // ---- glu + fp32 skip + LN + weighted combine (regs only) ----
        float y[32];
        #pragma unroll
        for (int q = 0; q < 4; ++q) {
            y[q * 4 + 0] = sk[q].x;     y[q * 4 + 1] = sk[q].y;
            y[q * 4 + 2] = sk[q].z;     y[q * 4 + 3] = sk[q].w;
            y[16 + q * 4 + 0] = sk[4 + q].x; y[16 + q * 4 + 1] = sk[4 + q].y;
            y[16 + q * 4 + 2] = sk[4 + q].z; y[16 + q * 4 + 3] = sk[4 + q].w;
        }
        #pragma unroll
        for (int r = 0; r < 16; ++r) {
            y[r]      += g0[r] * __builtin_amdgcn_rcpf(1.f + __expf(-g2[r]));
            y[16 + r] += g1[r] * __builtin_amdgcn_rcpf(1.f + __expf(-g3[r]));
        }
        float s1 = 0.f;
        #pragma unroll
        for (int i = 0; i < 32; ++i) s1 += y[i];
        s1 += __shfl_xor(s1, 32);
        float mean = s1 * (1.f / 64.f);
        float s2 = 0.f;
        #pragma unroll
        for (int i = 0; i < 32; ++i) { float d = y[i] - mean; s2 += d * d; }
        s2 += __shfl_xor(s2, 32);
        float rinv = __builtin_amdgcn_rsqf(s2 * (1.f / 64.f) + 1e-5f);
        const float* gbp = gb2[it & 1];
        #pragma unroll
        for (int r = 0; r < 16; ++r) {
            int hr = (r & 3) + 8 * (r >> 2) + 4 * s;
            float pv0 = (y[r]      - mean) * rinv * gbp[2 * hr]        + gbp[2 * hr + 1];
            float pv1 = (y[16 + r] - mean) * rinv * gbp[2 * (hr + 32)] + gbp[2 * (hr + 32) + 1];
            outacc[r]      += wvv * pv0;
            outacc[16 + r] += wvv * pv1;
        }
    }
    // ---- combine the two v-half blocks via atomics ----
    #pragma unroll
    for (int r = 0; r < 16; ++r) {
        int hr = (r & 3) + 8 * (r >> 2) + 4 * s;
        atomicAdd(out + tokg * 64 + hr,      outacc[r]);
        atomicAdd(out + tokg * 64 + 32 + hr, outacc[16 + r]);
    }
}

// ============================================================================
extern "C" void kernel_launch(void* const* d_in, const int* in_sizes, int n_in,
                              void* d_out, int out_size, void* d_ws, size_t ws_size,
                              hipStream_t stream) {
    const float* x        = (const float*)d_in[0];
    const float* wg_W1    = (const float*)d_in[1];
    const float* wg_b1    = (const float*)d_in[2];
    const float* wg_W2    = (const float*)d_in[3];
    const float* wg_b2    = (const float*)d_in[4];
    const float* wg_Wg    = (const float*)d_in[5];
    const float* wg_bg    = (const float*)d_in[6];
    const float* wg_Ws    = (const float*)d_in[7];
    const float* wg_bs    = (const float*)d_in[8];
    const float* wg_gamma = (const float*)d_in[9];
    const float* wg_beta  = (const float*)d_in[10];
    const float* v_W1     = (const float*)d_in[11];
    const float* v_b1     = (const float*)d_in[12];
    const float* v_W2     = (const float*)d_in[13];
    const float* v_b2     = (const float*)d_in[14];
    const float* v_Wg     = (const float*)d_in[15];
    const float* v_bg     = (const float*)d_in[16];
    const float* v_gamma  = (const float*)d_in[17];
    const float* v_beta   = (const float*)d_in[18];
    (void)in_sizes; (void)n_in; (void)ws_size;

    char* ws = (char*)d_ws;
    float* S               = (float*)(ws + WS_S);
    float* wbuf            = (float*)(ws + WS_WBUF);
    unsigned short* WcombT = (unsigned short*)(ws + WS_WCOMBT);
    unsigned short* wAv    = (unsigned short*)(ws + WS_WAV);
    float* out             = (float*)d_out;

    hipMemsetAsync(d_out, 0, (size_t)out_size * sizeof(float), stream);
    k0_prep<<<512, 256, 0, stream>>>(wg_W1, wg_Ws, v_W1, v_b1, v_W2, v_b2, v_Wg, v_bg,
                                     WcombT, wAv);
    k1_wgemm<<<1024, 256, 0, stream>>>(x, WcombT, wg_bs, wg_b1, S);
    k2_token<<<8192, 256, 0, stream>>>(S, wg_W2, wg_b2, wg_Wg, wg_bg, wg_gamma, wg_beta, wbuf);
    k3_vgrn<<<512, 256, 0, stream>>>(x, wAv, v_gamma, v_beta, wbuf, out);
}

// Round 3
// 621.782 us; speedup vs baseline: 1.4967x; 1.0423x over previous
//
#include <hip/hip_runtime.h>

// Problem constants (fixed by setup_inputs)
#define NT   32768      // B*T tokens
#define NV   32         // V
#define DI   64         // I == H
#define VI   2048       // V*I

typedef __attribute__((ext_vector_type(8)))  short short8;    // 8 bf16 (4 VGPRs)
typedef __attribute__((ext_vector_type(16))) float floatx16;  // MFMA 32x32 acc

#define MFMA32(a,b,c) __builtin_amdgcn_mfma_f32_32x32x16_bf16(a, b, c, 0, 0, 0)

// ---- workspace layout (bytes) ----
// S     : fp32 [NT][64]  (skip|elu(h1))          @ 0         (8,388,608)
// wbuf  : fp32 [NT][32]  (softmax weights)       @ 8388608   (4,194,304)
// WcombT: bf16 [64][2048] (A for weight GEMM)    @ 12582912  (262,144)
// wAv   : bf16 [32][256][88] (augmented A tiles) @ 12845056  (1,441,792)
#define WS_S      0
#define WS_WBUF   8388608
#define WS_WCOMBT 12582912
#define WS_WAV    12845056

// async global->LDS, 16B/lane; LDS dest = wave-uniform base + lane*16 (m104/m108)
#define GLDS(g, l) __builtin_amdgcn_global_load_lds( \
    (const __attribute__((address_space(1))) unsigned int*)(g), \
    (__attribute__((address_space(3))) unsigned int*)(l), 16, 0, 0)

static __device__ __forceinline__ unsigned short f2bf(float f) {
    union { float f; unsigned u; } v; v.f = f;
    unsigned r = v.u + 0x7FFFu + ((v.u >> 16) & 1u);   // RNE
    return (unsigned short)(r >> 16);
}
static __device__ __forceinline__ unsigned pk2bf(float lo, float hi) {
    return (unsigned)f2bf(lo) | ((unsigned)f2bf(hi) << 16);
}
// single-instruction packed f32->bf16 (RNE)
static __device__ __forceinline__ unsigned cvtpk(float lo, float hi) {
    unsigned r;
    asm("v_cvt_pk_bf16_f32 %0, %1, %2" : "=v"(r) : "v"(lo), "v"(hi));
    return r;
}
static __device__ __forceinline__ float elu1(float v) {
    return (v > 0.f) ? v : (__expf(v) - 1.f);
}

// ============================================================================
// K0: convert + transpose + bias-augment weights to bf16 in ws.
//  WcombT[n][k] = n<32 ? Ws[k][n] : W1[k][n-32]
//  wAv[v][r][c]: r<64: W1a (A[m=h][k=i], col64=b1), r<128: W2a, r>=128: Wga.
//  cols 65..87 zero (K padded to 80 in steps of 16; cols 80..87 never read).
// ============================================================================
__global__ void k0_prep(const float* __restrict__ wg_W1, const float* __restrict__ wg_Ws,
                        const float* __restrict__ v_W1, const float* __restrict__ v_b1,
                        const float* __restrict__ v_W2, const float* __restrict__ v_b2,
                        const float* __restrict__ v_Wg, const float* __restrict__ v_bg,
                        unsigned short* __restrict__ WcombT, unsigned short* __restrict__ wAv) {
    int tid = blockIdx.x * blockDim.x + threadIdx.x;
    int stride = gridDim.x * blockDim.x;
    for (int i = tid; i < 64 * 2048; i += stride) {
        int n = i >> 11, k = i & 2047;
        float val = (n < 32) ? wg_Ws[k * 32 + n] : wg_W1[k * 32 + (n - 32)];
        WcombT[i] = f2bf(val);
    }
    for (int i = tid; i < 32 * 256 * 88; i += stride) {
        int v  = i / (256 * 88);
        int rm = i - v * (256 * 88);
        int r  = rm / 88, c = rm - r * 88;
        float val = 0.f;
        if (r < 64) {
            if (c < 64)       val = v_W1[(v * 64 + c) * 64 + r];
            else if (c == 64) val = v_b1[v * 64 + r];
        } else if (r < 128) {
            int m = r - 64;
            if (c < 64)       val = v_W2[(v * 64 + c) * 64 + m];
            else if (c == 64) val = v_b2[v * 64 + m];
        } else {
            int m = r - 128;
            if (c < 64)       val = v_Wg[(v * 64 + c) * 128 + m];
            else if (c == 64) val = v_bg[v * 128 + m];
        }
        wAv[i] = f2bf(val);
    }
}

// ============================================================================
// K1: S = [skip | elu(h1)] = flat @ [Ws|W1] + [bs|b1], M=32768 K=2048 N=64.
// ============================================================================
__launch_bounds__(256, 4)
__global__ void k1_wgemm(const float* __restrict__ x, const unsigned short* __restrict__ WcombT,
                         const float* __restrict__ wg_bs, const float* __restrict__ wg_b1,
                         float* __restrict__ S) {
    __shared__ float Cbuf[4 * 64 * 33];   // [wave][outdim 64][tok 32+pad]
    int tid  = threadIdx.x;
    int wv   = tid >> 6;
    int lane = tid & 63;
    int l31  = lane & 31, s = lane >> 5;
    int tile = blockIdx.x;                             // 1024 tiles x 32 tokens
    long tok = (long)tile * 32 + l31;

    const float*          xrow = x + tok * VI + wv * 512 + s * 8;
    const unsigned short* a0p  = WcombT + (l31)      * 2048 + wv * 512 + s * 8;
    const unsigned short* a1p  = WcombT + (l31 + 32) * 2048 + wv * 512 + s * 8;

    floatx16 acc0 = {}; floatx16 acc1 = {};
    #pragma unroll 4
    for (int ks = 0; ks < 32; ++ks) {
        int ko = ks * 16;
        short8 af0 = *(const short8*)(a0p + ko);
        short8 af1 = *(const short8*)(a1p + ko);
        float4 xa = *(const float4*)(xrow + ko);
        float4 xb = *(const float4*)(xrow + ko + 4);
        union { unsigned u[4]; short8 s8; } bp;
        bp.u[0] = pk2bf(xa.x, xa.y);
        bp.u[1] = pk2bf(xa.z, xa.w);
        bp.u[2] = pk2bf(xb.x, xb.y);
        bp.u[3] = pk2bf(xb.z, xb.w);
        acc0 = MFMA32(af0, bp.s8, acc0);
        acc1 = MFMA32(af1, bp.s8, acc1);
    }
    // partial C -> LDS.  C layout: col=lane&31(tok), row=(reg&3)+8*(reg>>2)+4*s
    float* cb = Cbuf + wv * (64 * 33);
    #pragma unroll
    for (int reg = 0; reg < 16; ++reg) {
        int r0 = (reg & 3) + 8 * (reg >> 2) + 4 * s;
        cb[(r0)*33 + l31]      = acc0[reg];
        cb[(r0 + 32)*33 + l31] = acc1[reg];
    }
    __syncthreads();
    // reduce 4 K-partials + bias/elu epilogue; coalesced stores
    int n  = tid & 63;
    int tb = (tid >> 6) * 8;
    #pragma unroll
    for (int g = 0; g < 8; ++g) {
        int t = tb + g;
        float v = Cbuf[0*2112 + n*33 + t] + Cbuf[1*2112 + n*33 + t]
                + Cbuf[2*2112 + n*33 + t] + Cbuf[3*2112 + n*33 + t];
        if (n < 32) v += wg_bs[n];
        else        v = elu1(v + wg_b1[n - 32]);
        S[((long)tile * 32 + t) * 64 + n] = v;
    }
}

// ============================================================================
// K2: per-token h2 = h1e@W2+b2 ; z = h2@Wg+bg ; w = softmax(LN(skip+glu(z)))
// ============================================================================
__launch_bounds__(256, 4)
__global__ void k2_token(const float* __restrict__ S,
                         const float* __restrict__ wg_W2, const float* __restrict__ wg_b2,
                         const float* __restrict__ wg_Wg, const float* __restrict__ wg_bg,
                         const float* __restrict__ wg_gamma, const float* __restrict__ wg_beta,
                         float* __restrict__ wout) {
    int tid = threadIdx.x;
    int wv = tid >> 6, lane = tid & 63;
    int l31 = lane & 31;
    long t = (long)blockIdx.x * 4 + wv;
    float sv = S[t * 64 + lane];
    float h2 = wg_b2[l31];
    #pragma unroll
    for (int k = 0; k < 32; ++k) {
        float h1e = __shfl(sv, 32 + k);
        h2 += h1e * wg_W2[k * 32 + l31];
    }
    float z = wg_bg[lane];
    #pragma unroll
    for (int k = 0; k < 32; ++k) {
        float hk = __shfl(h2, k);
        z += hk * wg_Wg[k * 64 + lane];
    }
    float za   = __shfl(z, l31);
    float zg   = __shfl(z, l31 + 32);
    float skip = __shfl(sv, l31);
    float y = skip + za / (1.f + __expf(-zg));      // skip + glu(z)
    float s1 = y;
    #pragma unroll
    for (int m = 1; m <= 16; m <<= 1) s1 += __shfl_xor(s1, m);
    float mean = s1 * (1.f / 32.f);
    float d = y - mean;
    float s2 = d * d;
    #pragma unroll
    for (int m = 1; m <= 16; m <<= 1) s2 += __shfl_xor(s2, m);
    float rinv  = rsqrtf(s2 * (1.f / 32.f) + 1e-5f);
    float logit = d * rinv * wg_gamma[l31] + wg_beta[l31];
    float mx = logit;
    #pragma unroll
    for (int m = 1; m <= 16; m <<= 1) mx = fmaxf(mx, __shfl_xor(mx, m));
    float e = __expf(logit - mx);
    float se = e;
    #pragma unroll
    for (int m = 1; m <= 16; m <<= 1) se += __shfl_xor(se, m);
    if (lane < 32) wout[t * 32 + lane] = e / se;
}

// ============================================================================
// K3: per-variable GRNs + weighted combine (transposed MFMA chain).
// v4: full double-buffer pipeline, one block per CU, no atomics.
//  - 256 blocks, each owns one 128-token tile and loops ALL 32 vars ->
//    var-sum completes in-register: plain stores, no memset, no atomics,
//    no multi-round tail.
//  - LDS 153 KB: xt2 2x32KB + wA2 2x44KB + gb2 2x0.5KB -> 1 block/CU.
//  - ONE __syncthreads per iteration: staging for var i+1 is issued at the
//    TOP of iteration i into the idle buffer, flies across the ENTIRE
//    GEMM-chain+epilogue (~4k cyc), and is drained by the compiler's
//    vmcnt(0)-before-s_barrier at the bottom. (v3 single-buffer only
//    overlapped the short epilogue -> 29k cyc/iter, 70% idle.)
//  - xt linear [128][64] with 16B-granule XOR swizzle (phys = log ^ (row&7))
//    applied at the GLOBAL source during GLDS and on every LDS read
//    (both-sides involution, rule #21). wA stride 88 (odd granule count ->
//    conflict-free b128 A-frag reads).
// ============================================================================
static __device__ __forceinline__ void tile_to_bfrags(const float* t16, int sh,
                                                      short8* f0, short8* f1) {
    unsigned P[8];
    #pragma unroll
    for (int i = 0; i < 8; ++i) P[i] = cvtpk(t16[2 * i], t16[2 * i + 1]);
    unsigned X[8];
    #pragma unroll
    for (int i = 0; i < 8; ++i) X[i] = (unsigned)__shfl_xor((int)P[i], 32);
    union { unsigned u[4]; short8 s8; } a, b;
    a.u[0] = sh ? X[2] : P[0];  a.u[1] = sh ? X[3] : P[1];
    a.u[2] = sh ? P[2] : X[0];  a.u[3] = sh ? P[3] : X[1];
    b.u[0] = sh ? X[6] : P[4];  b.u[1] = sh ? X[7] : P[5];
    b.u[2] = sh ? P[6] : X[4];  b.u[3] = sh ? P[7] : X[5];
    *f0 = a.s8; *f1 = b.s8;
}

__launch_bounds__(256, 1)
__global__ void k3_vgrn(const float* __restrict__ x, const unsigned short* __restrict__ wAv,
                        const float* __restrict__ v_gamma, const float* __restrict__ v_beta,
                        const float* __restrict__ wbuf, float* __restrict__ out) {
    __shared__ __align__(16) float xt2[2][128 * 64];            // 64 KB dbuf x tile
    __shared__ __align__(16) unsigned short wA2[2][256 * 88];   // 88 KB dbuf weights
    __shared__ float gb2[2][128];                               // 1 KB dbuf gamma/beta
    int tid  = threadIdx.x;
    int wv   = tid >> 6, lane = tid & 63;
    int l31  = lane & 31, s = lane >> 5;
    int tile = blockIdx.x;                               // 256 token tiles
    int tl   = wv * 32 + l31;                            // token within tile
    int tl7  = tl & 7;
    long tokg = (long)tile * 128 + tl;

    float outacc[32];
    #pragma unroll
    for (int i = 0; i < 32; ++i) outacc[i] = 0.f;

    // ones B-frag: k=64 (bias col) -> s=0,j=0 only
    union { unsigned u[4]; short8 s8; } onef;
    onef.u[0] = (s == 0) ? 0x00003F80u : 0u;
    onef.u[1] = 0; onef.u[2] = 0; onef.u[3] = 0;

    const float* xbase = x + (long)tile * 128 * VI;

    // staging: 8 GLDS (x, swizzled source) + 11 GLDS (wA) + gamma/beta
    auto STAGE = [&](int b, int vg2) {
        const float* xv = xbase + (long)vg2 * DI;
        char* xdst = (char*)(&xt2[b][0]) + wv * 8192;
        #pragma unroll
        for (int i = 0; i < 8; ++i) {
            int g = i * 64 + lane;
            int row = wv * 32 + (g >> 4);
            int unit = g & 15;
            GLDS(xv + (long)row * VI + ((unit ^ (row & 7)) << 2), xdst + i * 1024);
        }
        const char* wsv = (const char*)wAv + (size_t)vg2 * 45056 + wv * 11264 + lane * 16;
        char* wdl = (char*)(&wA2[b][0]) + wv * 11264;
        #pragma unroll
        for (int i = 0; i < 11; ++i) GLDS(wsv + i * 1024, wdl + i * 1024);
        if (tid < 128) {
            int h = tid >> 1;
            gb2[b][tid] = (tid & 1) ? v_beta[vg2 * 64 + h] : v_gamma[vg2 * 64 + h];
        }
    };

    // ---- prologue: stage var 0 into buffer 0 ----
    STAGE(0, 0);
    __syncthreads();        // vmcnt(0) drain + barrier

    for (int it = 0; it < 32; ++it) {
        int c = it & 1;
        // ---- issue next var's staging into the idle buffer (T3/T14):
        //      flies across the whole GEMM chain + epilogue below ----
        if (it < 31) STAGE(c ^ 1, it + 1);

        const float* xrl = &xt2[c][0] + tl * 64;
        const unsigned short* wArow = &wA2[c][0] + l31 * 88 + s * 8;

        // ---- x B-frags (4 ksteps of 16), swizzled reads ----
        short8 xb4[4];
        #pragma unroll
        for (int ks = 0; ks < 4; ++ks) {
            int u0 = 2 * s + 4 * ks;
            float4 xa = *(const float4*)(xrl + ((u0 ^ tl7) << 2));
            float4 xc = *(const float4*)(xrl + (((u0 + 1) ^ tl7) << 2));
            union { unsigned u[4]; short8 s8; } bp;
            bp.u[0] = cvtpk(xa.x, xa.y);
            bp.u[1] = cvtpk(xa.z, xa.w);
            bp.u[2] = cvtpk(xc.x, xc.y);
            bp.u[3] = cvtpk(xc.z, xc.w);
            xb4[ks] = bp.s8;
        }

        // ---- H1T = W1a @ [XT;1] ----
        floatx16 h1a0 = {}, h1a1 = {};
        #pragma unroll
        for (int ks = 0; ks < 5; ++ks) {
            short8 b = (ks < 4) ? xb4[ks] : onef.s8;
            h1a0 = MFMA32(*(const short8*)(wArow + (0)  * 88 + ks * 16), b, h1a0);
            h1a1 = MFMA32(*(const short8*)(wArow + (32) * 88 + ks * 16), b, h1a1);
        }
        short8 h1b[4];
        {
            float t16[16];
            #pragma unroll
            for (int r = 0; r < 16; ++r) t16[r] = elu1(h1a0[r]);
            tile_to_bfrags(t16, s, &h1b[0], &h1b[1]);
            #pragma unroll
            for (int r = 0; r < 16; ++r) t16[r] = elu1(h1a1[r]);
            tile_to_bfrags(t16, s, &h1b[2], &h1b[3]);
        }
        // ---- H2T = W2a @ [H1T;1] ----
        floatx16 h2a0 = {}, h2a1 = {};
        #pragma unroll
        for (int ks = 0; ks < 5; ++ks) {
            short8 b = (ks < 4) ? h1b[ks] : onef.s8;
            h2a0 = MFMA32(*(const short8*)(wArow + (64) * 88 + ks * 16), b, h2a0);
            h2a1 = MFMA32(*(const short8*)(wArow + (96) * 88 + ks * 16), b, h2a1);
        }
        short8 h2b[4];
        {
            float t16[16];
            #pragma unroll
            for (int r = 0; r < 16; ++r) t16[r] = h2a0[r];
            tile_to_bfrags(t16, s, &h2b[0], &h2b[1]);
            #pragma unroll
            for (int r = 0; r < 16; ++r) t16[r] = h2a1[r];
            tile_to_bfrags(t16, s, &h2b[2], &h2b[3]);
        }
        // ---- GT = Wga @ [H2T;1] : rows 0..63 = a, 64..127 = gate ----
        floatx16 g0 = {}, g1 = {}, g2 = {}, g3 = {};
        #pragma unroll
        for (int ks = 0; ks < 5; ++ks) {
            short8 b = (ks < 4) ? h2b[ks] : onef.s8;
            g0 = MFMA32(*(const short8*)(wArow + (128) * 88 + ks * 16), b, g0);
            g1 = MFMA32(*(const short8*)(wArow + (160) * 88 + ks * 16), b, g1);
            g2 = MFMA32(*(const short8*)(wArow + (192) * 88 + ks * 16), b, g2);
            g3 = MFMA32(*(const short8*)(wArow + (224) * 88 + ks * 16), b, g3);
        }

        // ---- glu + fp32 skip (from compute buffer, safe under dbuf) + LN ----
        float y[32];
        #pragma unroll
        for (int q = 0; q < 8; ++q) {
            int u = (s + 2 * q) ^ tl7;
            float4 sk = *(const float4*)(xrl + (u << 2));
            int base = (q & 4) ? 16 + (q & 3) * 4 : (q & 3) * 4;
            y[base + 0] = sk.x; y[base + 1] = sk.y;
            y[base + 2] = sk.z; y[base + 3] = sk.w;
        }
        #pragma unroll
        for (int r = 0; r < 16; ++r) {
            y[r]      += g0[r] * __builtin_amdgcn_rcpf(1.f + __expf(-g2[r]));
            y[16 + r] += g1[r] * __builtin_amdgcn_rcpf(1.f + __expf(-g3[r]));
        }
        float s1 = 0.f;
        #pragma unroll
        for (int i = 0; i < 32; ++i) s1 += y[i];
        s1 += __shfl_xor(s1, 32);
        float mean = s1 * (1.f / 64.f);
        float s2 = 0.f;
        #pragma unroll
        for (int i = 0; i < 32; ++i) { float d = y[i] - mean; s2 += d * d; }
        s2 += __shfl_xor(s2, 32);
        float rinv = __builtin_amdgcn_rsqf(s2 * (1.f / 64.f) + 1e-5f);
        float wvv = wbuf[tokg * 32 + it];
        const float* gbp = gb2[c];
        #pragma unroll
        for (int r = 0; r < 16; ++r) {
            int hr = (r & 3) + 8 * (r >> 2) + 4 * s;
            float pv0 = (y[r]      - mean) * rinv * gbp[2 * hr]        + gbp[2 * hr + 1];
            float pv1 = (y[16 + r] - mean) * rinv * gbp[2 * (hr + 32)] + gbp[2 * (hr + 32) + 1];
            outacc[r]      += wvv * pv0;
            outacc[16 + r] += wvv * pv1;
        }

        __syncthreads();    // drains my 19 GLDS for it+1; buffers swap
    }

    // ---- full var-sum done in-register: plain stores ----
    #pragma unroll
    for (int r = 0; r < 16; ++r) {
        int hr = (r & 3) + 8 * (r >> 2) + 4 * s;
        out[tokg * 64 + hr]      = outacc[r];
        out[tokg * 64 + 32 + hr] = outacc[16 + r];
    }
}

// ============================================================================
extern "C" void kernel_launch(void* const* d_in, const int* in_sizes, int n_in,
                              void* d_out, int out_size, void* d_ws, size_t ws_size,
                              hipStream_t stream) {
    const float* x        = (const float*)d_in[0];
    const float* wg_W1    = (const float*)d_in[1];
    const float* wg_b1    = (const float*)d_in[2];
    const float* wg_W2    = (const float*)d_in[3];
    const float* wg_b2    = (const float*)d_in[4];
    const float* wg_Wg    = (const float*)d_in[5];
    const float* wg_bg    = (const float*)d_in[6];
    const float* wg_Ws    = (const float*)d_in[7];
    const float* wg_bs    = (const float*)d_in[8];
    const float* wg_gamma = (const float*)d_in[9];
    const float* wg_beta  = (const float*)d_in[10];
    const float* v_W1     = (const float*)d_in[11];
    const float* v_b1     = (const float*)d_in[12];
    const float* v_W2     = (const float*)d_in[13];
    const float* v_b2     = (const float*)d_in[14];
    const float* v_Wg     = (const float*)d_in[15];
    const float* v_bg     = (const float*)d_in[16];
    const float* v_gamma  = (const float*)d_in[17];
    const float* v_beta   = (const float*)d_in[18];
    (void)in_sizes; (void)n_in; (void)ws_size;

    char* ws = (char*)d_ws;
    float* S               = (float*)(ws + WS_S);
    float* wbuf            = (float*)(ws + WS_WBUF);
    unsigned short* WcombT = (unsigned short*)(ws + WS_WCOMBT);
    unsigned short* wAv    = (unsigned short*)(ws + WS_WAV);
    float* out             = (float*)d_out;

    k0_prep<<<512, 256, 0, stream>>>(wg_W1, wg_Ws, v_W1, v_b1, v_W2, v_b2, v_Wg, v_bg,
                                     WcombT, wAv);
    k1_wgemm<<<1024, 256, 0, stream>>>(x, WcombT, wg_bs, wg_b1, S);
    k2_token<<<8192, 256, 0, stream>>>(S, wg_W2, wg_b2, wg_Wg, wg_bg, wg_gamma, wg_beta, wbuf);
    k3_vgrn<<<256, 256, 0, stream>>>(x, wAv, v_gamma, v_beta, wbuf, out);
}

// Round 4
// 607.964 us; speedup vs baseline: 1.5307x; 1.0227x over previous
//
#include <hip/hip_runtime.h>

// Problem constants (fixed by setup_inputs)
#define NT   32768      // B*T tokens
#define NV   32         // V
#define DI   64         // I == H
#define VI   2048       // V*I

typedef __attribute__((ext_vector_type(8)))  short short8;    // 8 bf16 (4 VGPRs)
typedef __attribute__((ext_vector_type(16))) float floatx16;  // MFMA 32x32 acc

#define MFMA32(a,b,c) __builtin_amdgcn_mfma_f32_32x32x16_bf16(a, b, c, 0, 0, 0)

// ---- workspace layout (bytes) ----
#define WS_S      0
#define WS_WBUF   8388608
#define WS_WCOMBT 12582912
#define WS_WAV    12845056

// async global->LDS, 16B/lane; LDS dest = wave-uniform base + lane*16 (m104/m108)
#define GLDS(g, l) __builtin_amdgcn_global_load_lds( \
    (const __attribute__((address_space(1))) unsigned int*)(g), \
    (__attribute__((address_space(3))) unsigned int*)(l), 16, 0, 0)

static __device__ __forceinline__ unsigned short f2bf(float f) {
    union { float f; unsigned u; } v; v.f = f;
    unsigned r = v.u + 0x7FFFu + ((v.u >> 16) & 1u);   // RNE
    return (unsigned short)(r >> 16);
}
static __device__ __forceinline__ unsigned pk2bf(float lo, float hi) {
    return (unsigned)f2bf(lo) | ((unsigned)f2bf(hi) << 16);
}
// single-instruction packed f32->bf16 (RNE)
static __device__ __forceinline__ unsigned cvtpk(float lo, float hi) {
    unsigned r;
    asm("v_cvt_pk_bf16_f32 %0, %1, %2" : "=v"(r) : "v"(lo), "v"(hi));
    return r;
}
static __device__ __forceinline__ float elu1(float v) {
    return (v > 0.f) ? v : (__expf(v) - 1.f);
}

// ============================================================================
// K0: convert + transpose + bias-augment weights to bf16 in ws.
// ============================================================================
__global__ void k0_prep(const float* __restrict__ wg_W1, const float* __restrict__ wg_Ws,
                        const float* __restrict__ v_W1, const float* __restrict__ v_b1,
                        const float* __restrict__ v_W2, const float* __restrict__ v_b2,
                        const float* __restrict__ v_Wg, const float* __restrict__ v_bg,
                        unsigned short* __restrict__ WcombT, unsigned short* __restrict__ wAv) {
    int tid = blockIdx.x * blockDim.x + threadIdx.x;
    int stride = gridDim.x * blockDim.x;
    for (int i = tid; i < 64 * 2048; i += stride) {
        int n = i >> 11, k = i & 2047;
        float val = (n < 32) ? wg_Ws[k * 32 + n] : wg_W1[k * 32 + (n - 32)];
        WcombT[i] = f2bf(val);
    }
    for (int i = tid; i < 32 * 256 * 88; i += stride) {
        int v  = i / (256 * 88);
        int rm = i - v * (256 * 88);
        int r  = rm / 88, c = rm - r * 88;
        float val = 0.f;
        if (r < 64) {
            if (c < 64)       val = v_W1[(v * 64 + c) * 64 + r];
            else if (c == 64) val = v_b1[v * 64 + r];
        } else if (r < 128) {
            int m = r - 64;
            if (c < 64)       val = v_W2[(v * 64 + c) * 64 + m];
            else if (c == 64) val = v_b2[v * 64 + m];
        } else {
            int m = r - 128;
            if (c < 64)       val = v_Wg[(v * 64 + c) * 128 + m];
            else if (c == 64) val = v_bg[v * 128 + m];
        }
        wAv[i] = f2bf(val);
    }
}

// ============================================================================
// K1: S = [skip | elu(h1)] = flat @ [Ws|W1] + [bs|b1], M=32768 K=2048 N=64.
// ============================================================================
__launch_bounds__(256, 4)
__global__ void k1_wgemm(const float* __restrict__ x, const unsigned short* __restrict__ WcombT,
                         const float* __restrict__ wg_bs, const float* __restrict__ wg_b1,
                         float* __restrict__ S) {
    __shared__ float Cbuf[4 * 64 * 33];   // [wave][outdim 64][tok 32+pad]
    int tid  = threadIdx.x;
    int wv   = tid >> 6;
    int lane = tid & 63;
    int l31  = lane & 31, s = lane >> 5;
    int tile = blockIdx.x;                             // 1024 tiles x 32 tokens
    long tok = (long)tile * 32 + l31;

    const float*          xrow = x + tok * VI + wv * 512 + s * 8;
    const unsigned short* a0p  = WcombT + (l31)      * 2048 + wv * 512 + s * 8;
    const unsigned short* a1p  = WcombT + (l31 + 32) * 2048 + wv * 512 + s * 8;

    floatx16 acc0 = {}; floatx16 acc1 = {};
    #pragma unroll 4
    for (int ks = 0; ks < 32; ++ks) {
        int ko = ks * 16;
        short8 af0 = *(const short8*)(a0p + ko);
        short8 af1 = *(const short8*)(a1p + ko);
        float4 xa = *(const float4*)(xrow + ko);
        float4 xb = *(const float4*)(xrow + ko + 4);
        union { unsigned u[4]; short8 s8; } bp;
        bp.u[0] = pk2bf(xa.x, xa.y);
        bp.u[1] = pk2bf(xa.z, xa.w);
        bp.u[2] = pk2bf(xb.x, xb.y);
        bp.u[3] = pk2bf(xb.z, xb.w);
        acc0 = MFMA32(af0, bp.s8, acc0);
        acc1 = MFMA32(af1, bp.s8, acc1);
    }
    // partial C -> LDS.  C layout: col=lane&31(tok), row=(reg&3)+8*(reg>>2)+4*s
    float* cb = Cbuf + wv * (64 * 33);
    #pragma unroll
    for (int reg = 0; reg < 16; ++reg) {
        int r0 = (reg & 3) + 8 * (reg >> 2) + 4 * s;
        cb[(r0)*33 + l31]      = acc0[reg];
        cb[(r0 + 32)*33 + l31] = acc1[reg];
    }
    __syncthreads();
    int n  = tid & 63;
    int tb = (tid >> 6) * 8;
    #pragma unroll
    for (int g = 0; g < 8; ++g) {
        int t = tb + g;
        float v = Cbuf[0*2112 + n*33 + t] + Cbuf[1*2112 + n*33 + t]
                + Cbuf[2*2112 + n*33 + t] + Cbuf[3*2112 + n*33 + t];
        if (n < 32) v += wg_bs[n];
        else        v = elu1(v + wg_b1[n - 32]);
        S[((long)tile * 32 + t) * 64 + n] = v;
    }
}

// ============================================================================
// K2: per-token h2 = h1e@W2+b2 ; z = h2@Wg+bg ; w = softmax(LN(skip+glu(z)))
// ============================================================================
__launch_bounds__(256, 4)
__global__ void k2_token(const float* __restrict__ S,
                         const float* __restrict__ wg_W2, const float* __restrict__ wg_b2,
                         const float* __restrict__ wg_Wg, const float* __restrict__ wg_bg,
                         const float* __restrict__ wg_gamma, const float* __restrict__ wg_beta,
                         float* __restrict__ wout) {
    int tid = threadIdx.x;
    int wv = tid >> 6, lane = tid & 63;
    int l31 = lane & 31;
    long t = (long)blockIdx.x * 4 + wv;
    float sv = S[t * 64 + lane];
    float h2 = wg_b2[l31];
    #pragma unroll
    for (int k = 0; k < 32; ++k) {
        float h1e = __shfl(sv, 32 + k);
        h2 += h1e * wg_W2[k * 32 + l31];
    }
    float z = wg_bg[lane];
    #pragma unroll
    for (int k = 0; k < 32; ++k) {
        float hk = __shfl(h2, k);
        z += hk * wg_Wg[k * 64 + lane];
    }
    float za   = __shfl(z, l31);
    float zg   = __shfl(z, l31 + 32);
    float skip = __shfl(sv, l31);
    float y = skip + za / (1.f + __expf(-zg));      // skip + glu(z)
    float s1 = y;
    #pragma unroll
    for (int m = 1; m <= 16; m <<= 1) s1 += __shfl_xor(s1, m);
    float mean = s1 * (1.f / 32.f);
    float d = y - mean;
    float s2 = d * d;
    #pragma unroll
    for (int m = 1; m <= 16; m <<= 1) s2 += __shfl_xor(s2, m);
    float rinv  = rsqrtf(s2 * (1.f / 32.f) + 1e-5f);
    float logit = d * rinv * wg_gamma[l31] + wg_beta[l31];
    float mx = logit;
    #pragma unroll
    for (int m = 1; m <= 16; m <<= 1) mx = fmaxf(mx, __shfl_xor(mx, m));
    float e = __expf(logit - mx);
    float se = e;
    #pragma unroll
    for (int m = 1; m <= 16; m <<= 1) se += __shfl_xor(se, m);
    if (lane < 32) wout[t * 32 + lane] = e / se;
}

// ============================================================================
// K3: per-variable GRNs + weighted combine (transposed MFMA chain).
// v5: 8 waves / 512 threads -> 2 waves per SIMD (v4 had 1/SIMD: every
// latency in the serial chain was exposed -> MfmaUtil 10%, VALUBusy 31%).
//  - 256 blocks x 128 tokens x all 32 vars (x read once, no atomics).
//  - wave PAIR shares a 32-token tile: H1/H2 duplicated in both waves
//    (identical inputs -> identical regs, zero exchange); G + epilogue
//    split by output half (wave q: a-rows q*32.., gate-rows 64+q*32..,
//    output dims q*32..q*32+31).
//  - LN needs cross-wave mean/var: raw-moment partials (sum, sumsq)
//    exchanged via 2KB LDS + RAW s_barrier (lgkmcnt fence only, NO
//    __syncthreads -> in-flight GLDS staging is NOT drained mid-iter).
//  - staging (x swizzled + wA + gb) split across all 8 waves, issued at
//    iteration top into the idle buffer, drained by the single
//    end-of-iteration __syncthreads.
//  - LDS 158,720 B: xt2 64K + wA2 88K + gb2 1K + ln 2K -> 1 block/CU,
//    8 waves = 2/SIMD; __launch_bounds__(512,2) caps VGPR at 256.
// ============================================================================
static __device__ __forceinline__ void tile_to_bfrags(const float* t16, int sh,
                                                      short8* f0, short8* f1) {
    unsigned P[8];
    #pragma unroll
    for (int i = 0; i < 8; ++i) P[i] = cvtpk(t16[2 * i], t16[2 * i + 1]);
    unsigned X[8];
    #pragma unroll
    for (int i = 0; i < 8; ++i) X[i] = (unsigned)__shfl_xor((int)P[i], 32);
    union { unsigned u[4]; short8 s8; } a, b;
    a.u[0] = sh ? X[2] : P[0];  a.u[1] = sh ? X[3] : P[1];
    a.u[2] = sh ? P[2] : X[0];  a.u[3] = sh ? P[3] : X[1];
    b.u[0] = sh ? X[6] : P[4];  b.u[1] = sh ? X[7] : P[5];
    b.u[2] = sh ? P[6] : X[4];  b.u[3] = sh ? P[7] : X[5];
    *f0 = a.s8; *f1 = b.s8;
}

__launch_bounds__(512, 2)
__global__ void k3_vgrn(const float* __restrict__ x, const unsigned short* __restrict__ wAv,
                        const float* __restrict__ v_gamma, const float* __restrict__ v_beta,
                        const float* __restrict__ wbuf, float* __restrict__ out) {
    __shared__ __align__(16) float xt2[2][128 * 64];            // 64 KB dbuf x tile
    __shared__ __align__(16) unsigned short wA2[2][256 * 88];   // 88 KB dbuf weights
    __shared__ float gb2[2][128];                               // 1 KB dbuf gamma/beta
    __shared__ float lnP[2][4][2][32];                          // 2 KB LN partials
    int tid  = threadIdx.x;
    int wv   = tid >> 6, lane = tid & 63;
    int l31  = lane & 31, s = lane >> 5;
    int pair = wv >> 1, q = wv & 1;
    int tile = blockIdx.x;                               // 256 token tiles
    int tl   = pair * 32 + l31;                          // token within tile
    int tl7  = l31 & 7;
    long tokg = (long)tile * 128 + tl;

    float outacc[16];
    #pragma unroll
    for (int i = 0; i < 16; ++i) outacc[i] = 0.f;

    // ones B-frag: k=64 (bias col) -> s=0,j=0 only
    union { unsigned u[4]; short8 s8; } onef;
    onef.u[0] = (s == 0) ? 0x00003F80u : 0u;
    onef.u[1] = 0; onef.u[2] = 0; onef.u[3] = 0;

    const float* xbase = x + (long)tile * 128 * VI;
    int wbase = (tid >> 6) << 6;                         // wave-uniform tid base

    // staging split across 8 waves: x 2048 slots (4/thread), wA 2816 slots
    auto STAGE = [&](int b, int vg2) {
        const float* xv = xbase + (long)vg2 * DI;
        char* xd = (char*)(&xt2[b][0]);
        #pragma unroll
        for (int i = 0; i < 4; ++i) {
            int slot = i * 512 + tid;
            int row = slot >> 4, g = slot & 15;
            GLDS(xv + (long)row * VI + ((g ^ (row & 7)) << 2),
                 xd + (i * 512 + wbase) * 16);
        }
        const char* wsv = (const char*)wAv + (size_t)vg2 * 45056;
        char* wd = (char*)(&wA2[b][0]);
        #pragma unroll
        for (int i = 0; i < 6; ++i) {
            int slot = i * 512 + tid;
            if (slot < 2816)
                GLDS(wsv + (size_t)slot * 16, wd + (i * 512 + wbase) * 16);
        }
        if (tid < 128) {
            int h = tid >> 1;
            gb2[b][tid] = (tid & 1) ? v_beta[vg2 * 64 + h] : v_gamma[vg2 * 64 + h];
        }
    };

    // ---- prologue: stage var 0 into buffer 0 ----
    STAGE(0, 0);
    __syncthreads();        // vmcnt(0) drain + barrier

    for (int it = 0; it < 32; ++it) {
        int c = it & 1;
        // ---- issue next var's staging into the idle buffer; flies across
        //      the WHOLE iteration (raw mid-barrier does not drain vmcnt) ----
        if (it < 31) STAGE(c ^ 1, it + 1);

        const float* xrl = &xt2[c][0] + tl * 64;
        const unsigned short* wArow = &wA2[c][0] + l31 * 88 + s * 8;
        float wvv = wbuf[tokg * 32 + it];

        // ---- x B-frags (4 ksteps of 16), swizzled reads ----
        short8 xb4[4];
        #pragma unroll
        for (int ks = 0; ks < 4; ++ks) {
            int u0 = 2 * s + 4 * ks;
            float4 xa = *(const float4*)(xrl + ((u0 ^ tl7) << 2));
            float4 xc = *(const float4*)(xrl + (((u0 + 1) ^ tl7) << 2));
            union { unsigned u[4]; short8 s8; } bp;
            bp.u[0] = cvtpk(xa.x, xa.y);
            bp.u[1] = cvtpk(xa.z, xa.w);
            bp.u[2] = cvtpk(xc.x, xc.y);
            bp.u[3] = cvtpk(xc.z, xc.w);
            xb4[ks] = bp.s8;
        }

        // ---- H1T = W1a @ [XT;1]  (duplicated in both waves of the pair) ----
        floatx16 h1a0 = {}, h1a1 = {};
        #pragma unroll
        for (int ks = 0; ks < 5; ++ks) {
            short8 b = (ks < 4) ? xb4[ks] : onef.s8;
            h1a0 = MFMA32(*(const short8*)(wArow + (0)  * 88 + ks * 16), b, h1a0);
            h1a1 = MFMA32(*(const short8*)(wArow + (32) * 88 + ks * 16), b, h1a1);
        }
        short8 h1b[4];
        {
            float t16[16];
            #pragma unroll
            for (int r = 0; r < 16; ++r) t16[r] = elu1(h1a0[r]);
            tile_to_bfrags(t16, s, &h1b[0], &h1b[1]);
            #pragma unroll
            for (int r = 0; r < 16; ++r) t16[r] = elu1(h1a1[r]);
            tile_to_bfrags(t16, s, &h1b[2], &h1b[3]);
        }
        // ---- H2T = W2a @ [H1T;1]  (duplicated) ----
        floatx16 h2a0 = {}, h2a1 = {};
        #pragma unroll
        for (int ks = 0; ks < 5; ++ks) {
            short8 b = (ks < 4) ? h1b[ks] : onef.s8;
            h2a0 = MFMA32(*(const short8*)(wArow + (64) * 88 + ks * 16), b, h2a0);
            h2a1 = MFMA32(*(const short8*)(wArow + (96) * 88 + ks * 16), b, h2a1);
        }
        short8 h2b[4];
        {
            float t16[16];
            #pragma unroll
            for (int r = 0; r < 16; ++r) t16[r] = h2a0[r];
            tile_to_bfrags(t16, s, &h2b[0], &h2b[1]);
            #pragma unroll
            for (int r = 0; r < 16; ++r) t16[r] = h2a1[r];
            tile_to_bfrags(t16, s, &h2b[2], &h2b[3]);
        }
        // ---- G split by wave: a-rows 128+q*32, gate-rows 192+q*32 ----
        floatx16 ga = {}, gg = {};
        #pragma unroll
        for (int ks = 0; ks < 5; ++ks) {
            short8 b = (ks < 4) ? h2b[ks] : onef.s8;
            ga = MFMA32(*(const short8*)(wArow + (128 + q * 32) * 88 + ks * 16), b, ga);
            gg = MFMA32(*(const short8*)(wArow + (192 + q * 32) * 88 + ks * 16), b, gg);
        }

        // ---- skip (own 16 dims) + glu ----
        float y[16];
        #pragma unroll
        for (int j = 0; j < 4; ++j) {
            int gidx = q * 8 + s + 2 * j;
            float4 sk = *(const float4*)(xrl + ((gidx ^ tl7) << 2));
            y[j * 4 + 0] = sk.x; y[j * 4 + 1] = sk.y;
            y[j * 4 + 2] = sk.z; y[j * 4 + 3] = sk.w;
        }
        #pragma unroll
        for (int r = 0; r < 16; ++r)
            y[r] += ga[r] * __builtin_amdgcn_rcpf(1.f + __expf(-gg[r]));

        // ---- LN raw moments: own 32-dim partial, exchange with pair wave ----
        float s1 = 0.f, sq = 0.f;
        #pragma unroll
        for (int i = 0; i < 16; ++i) { s1 += y[i]; sq += y[i] * y[i]; }
        s1 += __shfl_xor(s1, 32);
        sq += __shfl_xor(sq, 32);
        if (s == 0) lnP[0][pair][q][l31] = s1;
        else        lnP[1][pair][q][l31] = sq;
        asm volatile("s_waitcnt lgkmcnt(0)" ::: "memory");
        __builtin_amdgcn_s_barrier();          // raw: does NOT drain vmcnt
        asm volatile("" ::: "memory");
        float o1 = lnP[0][pair][q ^ 1][l31];
        float o2 = lnP[1][pair][q ^ 1][l31];
        float mean = (s1 + o1) * (1.f / 64.f);
        float var  = (sq + o2) * (1.f / 64.f) - mean * mean;
        float rinv = __builtin_amdgcn_rsqf(var + 1e-5f);

        const float* gbp = gb2[c];
        #pragma unroll
        for (int r = 0; r < 16; ++r) {
            int d = q * 32 + (r & 3) + 8 * (r >> 2) + 4 * s;
            float pv = (y[r] - mean) * rinv * gbp[2 * d] + gbp[2 * d + 1];
            outacc[r] += wvv * pv;
        }

        __syncthreads();    // drains staging for it+1; buffers swap
    }

    // ---- full var-sum done in-register: float4 stores (own dims) ----
    #pragma unroll
    for (int j = 0; j < 4; ++j) {
        float4 o;
        o.x = outacc[j * 4 + 0]; o.y = outacc[j * 4 + 1];
        o.z = outacc[j * 4 + 2]; o.w = outacc[j * 4 + 3];
        *(float4*)(out + tokg * 64 + q * 32 + 4 * s + 8 * j) = o;
    }
}

// ============================================================================
extern "C" void kernel_launch(void* const* d_in, const int* in_sizes, int n_in,
                              void* d_out, int out_size, void* d_ws, size_t ws_size,
                              hipStream_t stream) {
    const float* x        = (const float*)d_in[0];
    const float* wg_W1    = (const float*)d_in[1];
    const float* wg_b1    = (const float*)d_in[2];
    const float* wg_W2    = (const float*)d_in[3];
    const float* wg_b2    = (const float*)d_in[4];
    const float* wg_Wg    = (const float*)d_in[5];
    const float* wg_bg    = (const float*)d_in[6];
    const float* wg_Ws    = (const float*)d_in[7];
    const float* wg_bs    = (const float*)d_in[8];
    const float* wg_gamma = (const float*)d_in[9];
    const float* wg_beta  = (const float*)d_in[10];
    const float* v_W1     = (const float*)d_in[11];
    const float* v_b1     = (const float*)d_in[12];
    const float* v_W2     = (const float*)d_in[13];
    const float* v_b2     = (const float*)d_in[14];
    const float* v_Wg     = (const float*)d_in[15];
    const float* v_bg     = (const float*)d_in[16];
    const float* v_gamma  = (const float*)d_in[17];
    const float* v_beta   = (const float*)d_in[18];
    (void)in_sizes; (void)n_in; (void)ws_size;

    char* ws = (char*)d_ws;
    float* S               = (float*)(ws + WS_S);
    float* wbuf            = (float*)(ws + WS_WBUF);
    unsigned short* WcombT = (unsigned short*)(ws + WS_WCOMBT);
    unsigned short* wAv    = (unsigned short*)(ws + WS_WAV);
    float* out             = (float*)d_out;

    k0_prep<<<512, 256, 0, stream>>>(wg_W1, wg_Ws, v_W1, v_b1, v_W2, v_b2, v_Wg, v_bg,
                                     WcombT, wAv);
    k1_wgemm<<<1024, 256, 0, stream>>>(x, WcombT, wg_bs, wg_b1, S);
    k2_token<<<8192, 256, 0, stream>>>(S, wg_W2, wg_b2, wg_Wg, wg_bg, wg_gamma, wg_beta, wbuf);
    k3_vgrn<<<256, 512, 0, stream>>>(x, wAv, v_gamma, v_beta, wbuf, out);
}